// Round 5
// baseline (352.646 us; speedup 1.0000x reference)
//
#include <hip/hip_runtime.h>
#include <math.h>

#define HW 16384
#define NPTS 1024
#define LOG_N 6.2383246250395075
#define RHO_C 0.09
#define SCALE_F 16384.0f
#define INV_SCALE2 3.725290298461914e-09  // 2^-28, exact
#define NTILES 36                          // 8x8 upper triangle
#define SINK_BLOCKS 256

typedef _Float16 f16x8 __attribute__((ext_vector_type(8)));
typedef float f32x4 __attribute__((ext_vector_type(4)));

typedef __attribute__((address_space(1))) const void gvoid_t;
typedef __attribute__((address_space(3))) void svoid_t;

__device__ __forceinline__ void tri_map(int tt, int& ti, int& tj) {
  int a = 0, r = tt;
  while (r >= 8 - a) { r -= 8 - a; ++a; }
  ti = a; tj = a + r;
}

// ---------------------------------------------------------------------------
// Convert fp32 P=[nd;gt] (1024 x 16384) into scaled fp16 hi/lo split, stored
// K-tiled: hi_t[k64][row][64], 8-elem groups pre-swizzled by g ^ (row&7) so
// the GEMM's linear global_load_lds yields a conflict-free LDS image.
// ---------------------------------------------------------------------------
__global__ __launch_bounds__(256)
void convert_split_k(const float* __restrict__ nd, const float* __restrict__ gt,
                     _Float16* __restrict__ hi_t, _Float16* __restrict__ lo_t) {
  const int tid = blockIdx.x * 256 + threadIdx.x;  // 0 .. 262143
  const int r = tid & 1023;
  const int k64 = tid >> 10;
  const float* __restrict__ src =
      (r < 512 ? nd + (size_t)r * HW : gt + (size_t)(r - 512) * HW) + k64 * 64;
  const size_t obase = ((size_t)k64 * 1024 + r) * 64;
  const int sw = r & 7;
#pragma unroll
  for (int g = 0; g < 8; ++g) {
    const float4 v0 = *(const float4*)(src + g * 8);
    const float4 v1 = *(const float4*)(src + g * 8 + 4);
    const float x[8] = {v0.x, v0.y, v0.z, v0.w, v1.x, v1.y, v1.z, v1.w};
    f16x8 h, l;
#pragma unroll
    for (int j = 0; j < 8; ++j) {
      const float xs = x[j] * SCALE_F;
      const _Float16 hh = (_Float16)xs;
      h[j] = hh;
      l[j] = (_Float16)(xs - (float)hh);
    }
    *(f16x8*)(hi_t + obase + (size_t)(g ^ sw) * 8) = h;
    *(f16x8*)(lo_t + obase + (size_t)(g ^ sw) * 8) = l;
  }
}

// ---------------------------------------------------------------------------
// Upper-triangle tiles only (G symmetric). 128x128 tile, BK=64, 4 waves,
// 3-pass f16 split MFMA. Split-K: gridDim.y chunks, UNEVEN (q or q+1 k64
// tiles each) so gridDim.x*gridDim.y can be held <= 512 (no dispatch tail:
// at 2 blocks/CU every block is co-resident -> inter-block latency hiding).
// ---------------------------------------------------------------------------
__global__ __launch_bounds__(256)
void gemm_mfma_k(const _Float16* __restrict__ hi_t, const _Float16* __restrict__ lo_t,
                 float* __restrict__ part) {
  __shared__ __align__(16) _Float16 Ahi[128 * 64];
  __shared__ __align__(16) _Float16 Alo[128 * 64];
  __shared__ __align__(16) _Float16 Bhi[128 * 64];
  __shared__ __align__(16) _Float16 Blo[128 * 64];

  const int tt = blockIdx.x, c = blockIdx.y;
  int ti, tj;
  tri_map(tt, ti, tj);
  const int ns = gridDim.y;
  const int q = 256 / ns, rm = 256 - q * ns;
  const int kt0 = c * q + min(c, rm);
  const int nkt = q + (c < rm ? 1 : 0);
  const int t = threadIdx.x;
  const int lane = t & 63, w = t >> 6;
  const int wr = w >> 1, wc = w & 1;

  f32x4 acc[4][4];
#pragma unroll
  for (int m = 0; m < 4; ++m)
#pragma unroll
    for (int n = 0; n < 4; ++n) acc[m][n] = (f32x4){0.f, 0.f, 0.f, 0.f};

  const int rlow = lane & 15, g0 = lane >> 4;

  for (int ks = 0; ks < nkt; ++ks) {
    const size_t ktbase = (size_t)(kt0 + ks) * (1024 * 64);
    const _Float16* __restrict__ sAh = hi_t + ktbase + (size_t)ti * 128 * 64;
    const _Float16* __restrict__ sAl = lo_t + ktbase + (size_t)ti * 128 * 64;
    const _Float16* __restrict__ sBh = hi_t + ktbase + (size_t)tj * 128 * 64;
    const _Float16* __restrict__ sBl = lo_t + ktbase + (size_t)tj * 128 * 64;
#pragma unroll
    for (int p = 0; p < 4; ++p) {
      const int off = (w * 4 + p) * 1024 + lane * 16;  // bytes
      __builtin_amdgcn_global_load_lds((gvoid_t*)((const char*)sAh + off),
                                       (svoid_t*)((char*)Ahi + (w * 4 + p) * 1024), 16, 0, 0);
      __builtin_amdgcn_global_load_lds((gvoid_t*)((const char*)sAl + off),
                                       (svoid_t*)((char*)Alo + (w * 4 + p) * 1024), 16, 0, 0);
      __builtin_amdgcn_global_load_lds((gvoid_t*)((const char*)sBh + off),
                                       (svoid_t*)((char*)Bhi + (w * 4 + p) * 1024), 16, 0, 0);
      __builtin_amdgcn_global_load_lds((gvoid_t*)((const char*)sBl + off),
                                       (svoid_t*)((char*)Blo + (w * 4 + p) * 1024), 16, 0, 0);
    }
    __syncthreads();

#pragma unroll
    for (int kk = 0; kk < 2; ++kk) {
      const int g = kk * 4 + g0;
      f16x8 fah[4], fal[4], fbh[4], fbl[4];
#pragma unroll
      for (int m = 0; m < 4; ++m) {
        const int ra = wr * 64 + m * 16 + rlow;
        const int pa = (g ^ (ra & 7)) * 8;
        fah[m] = *(const f16x8*)(Ahi + ra * 64 + pa);
        fal[m] = *(const f16x8*)(Alo + ra * 64 + pa);
        const int rb = wc * 64 + m * 16 + rlow;
        const int pb = (g ^ (rb & 7)) * 8;
        fbh[m] = *(const f16x8*)(Bhi + rb * 64 + pb);
        fbl[m] = *(const f16x8*)(Blo + rb * 64 + pb);
      }
#pragma unroll
      for (int m = 0; m < 4; ++m)
#pragma unroll
        for (int n = 0; n < 4; ++n) {
          acc[m][n] = __builtin_amdgcn_mfma_f32_16x16x32_f16(fah[m], fbh[n], acc[m][n], 0, 0, 0);
          acc[m][n] = __builtin_amdgcn_mfma_f32_16x16x32_f16(fal[m], fbh[n], acc[m][n], 0, 0, 0);
          acc[m][n] = __builtin_amdgcn_mfma_f32_16x16x32_f16(fah[m], fbl[n], acc[m][n], 0, 0, 0);
        }
    }
    __syncthreads();
  }

  // C/D layout: col = lane&15, row = (lane>>4)*4 + q (m89-verified)
  float* __restrict__ dst = part + ((size_t)c * NTILES + tt) * 16384;
  const int c_locb = wc * 64 + rlow;
  const int r_locb = wr * 64 + g0 * 4;
#pragma unroll
  for (int m = 0; m < 4; ++m)
#pragma unroll
    for (int p = 0; p < 4; ++p) {
      const int rl = r_locb + m * 16 + p;
#pragma unroll
      for (int n = 0; n < 4; ++n)
        dst[rl * 128 + c_locb + n * 16] = acc[m][n][p];
    }
}

// ---------------------------------------------------------------------------
// Sum split-K partials (fp64), unscale, write G tile + mirrored tile (LDS
// transpose), extract diagonal. Grid: 36 tiles x 16 slabs of 8 rows = 576.
// ---------------------------------------------------------------------------
__global__ __launch_bounds__(256)
void reduce_tiles_k(const float* __restrict__ part, float* __restrict__ G,
                    float* __restrict__ diag, int nsplit) {
  __shared__ float sl[8][129];
  const int blk = blockIdx.x;  // 0..575
  const int tt = blk >> 4, s = blk & 15;
  int ti, tj;
  tri_map(tt, ti, tj);
  const int t = threadIdx.x;
  const int base_in = tt * 16384 + s * 1024;

  float vals[4];
#pragma unroll
  for (int j = 0; j < 4; ++j) {
    const int idx = j * 256 + t;  // 0..1023 within slab
    double a = 0.0;
    for (int c = 0; c < nsplit; ++c)
      a += (double)part[(size_t)c * (NTILES * 16384) + base_in + idx];
    vals[j] = (float)(a * INV_SCALE2);
  }
#pragma unroll
  for (int j = 0; j < 4; ++j) {
    const int idx = j * 256 + t;
    const int r = idx >> 7, cl = idx & 127;
    const int R = ti * 128 + s * 8 + r, C = tj * 128 + cl;
    G[(size_t)R * NPTS + C] = vals[j];
    if (R == C) diag[R] = vals[j];
    sl[r][cl] = vals[j];
  }
  if (ti == tj) return;
  __syncthreads();
#pragma unroll
  for (int j = 0; j < 4; ++j) {
    const int idx = j * 256 + t;
    const int r = idx & 7, cl = idx >> 3;
    G[(size_t)(tj * 128 + cl) * NPTS + ti * 128 + s * 8 + r] = sl[r][cl];
  }
}

// ---------------------------------------------------------------------------
// Fused Sinkhorn: 11 phases + loss, ONE kernel, hand-rolled device-scope
// atomic barrier (round 3 measured cg::grid.sync() at ~52us/sync; this is
// ~1-2us). 256 blocks x 256 thr -- trivially all co-resident (0.5KB LDS,
// low VGPR). Bounded spin: a barrier failure produces a wrong answer (caught
// by validation), not a hang. C-rows live in registers across all phases.
// ---------------------------------------------------------------------------
__device__ __forceinline__ void grid_bar(unsigned* cnt, unsigned target) {
  __syncthreads();
  if (threadIdx.x == 0) {
    __threadfence();
    __hip_atomic_fetch_add(cnt, 1u, __ATOMIC_RELEASE, __HIP_MEMORY_SCOPE_AGENT);
    long spins = 0;
    while (__hip_atomic_load(cnt, __ATOMIC_ACQUIRE, __HIP_MEMORY_SCOPE_AGENT) < target &&
           spins < (1L << 31))
      { __builtin_amdgcn_s_sleep(8); ++spins; }
  }
  __syncthreads();
}

__global__ __launch_bounds__(256)
void sinkhorn_fused_k(const float* __restrict__ G, const float* __restrict__ diag,
                      double* __restrict__ pots, unsigned* __restrict__ cnt,
                      float* __restrict__ out, int out_size) {
  const int w = threadIdx.x >> 6, lane = threadIdx.x & 63;
  // 8 tasks per block: wave w handles tasks {blk*8 + w*2, blk*8 + w*2 + 1}
  int which[2], rr[2], pot_idx[2];
  double Creg[2][8];
#pragma unroll
  for (int s = 0; s < 2; ++s) {
    const int id = blockIdx.x * 8 + w * 2 + s;  // 0..2047
    which[s] = id >> 9;
    rr[s] = id & 511;
    int row_pt, col_base;
    if (which[s] == 0)      { row_pt = rr[s];       col_base = 512; pot_idx[s] = 1; }
    else if (which[s] == 1) { row_pt = 512 + rr[s]; col_base = 0;   pot_idx[s] = 0; }
    else if (which[s] == 2) { row_pt = rr[s];       col_base = 0;   pot_idx[s] = 2; }
    else                    { row_pt = 512 + rr[s]; col_base = 512; pot_idx[s] = 3; }
    const double dr = (double)diag[row_pt];
    const float* __restrict__ Grow = G + (size_t)row_pt * NPTS + col_base;
    const float* __restrict__ dcol = diag + col_base;
#pragma unroll
    for (int u = 0; u < 8; ++u) {
      const int j = lane + u * 64;
      Creg[s][u] = 0.5 * (dr + (double)dcol[j]) - (double)Grow[j];
    }
  }

  double* buf0 = pots;
  double* buf1 = pots + 2048;
  const double eps_tab[11] = {1.0, 1.0, 1.0, 0.25, 0.0625, 0.015625,
                              0.00390625, 0.0009765625, 0.000244140625, 1e-4, 1e-4};
#pragma unroll
  for (int p = 0; p < 11; ++p) {
    const double eps = eps_tab[p];
    const double inv_eps = 1.0 / eps;
    const double damp = 1.0 / (1.0 + eps / RHO_C);
    const int use_pot = (p > 0);
    const int do_avg = (p >= 1 && p <= 9);
    const double* __restrict__ sp = (p & 1) ? buf0 : buf1;
    double* __restrict__ dp = (p & 1) ? buf1 : buf0;
#pragma unroll
    for (int s = 0; s < 2; ++s) {
      const double* __restrict__ pot = sp + pot_idx[s] * 512;
      double arg[8];
      double m = -1.0e300;
#pragma unroll
      for (int u = 0; u < 8; ++u) {
        const double pv = use_pot ? pot[lane + u * 64] : 0.0;
        const double a = (pv - Creg[s][u]) * inv_eps - LOG_N;
        arg[u] = a;
        m = fmax(m, a);
      }
#pragma unroll
      for (int off = 32; off > 0; off >>= 1) m = fmax(m, __shfl_xor(m, off));
      double sm = 0.0;
#pragma unroll
      for (int u = 0; u < 8; ++u) sm += exp(arg[u] - m);
#pragma unroll
      for (int off = 32; off > 0; off >>= 1) sm += __shfl_xor(sm, off);
      if (lane == 0) {
        const double val = -eps * (m + log(sm)) * damp;
        dp[which[s] * 512 + rr[s]] =
            do_avg ? 0.5 * (sp[which[s] * 512 + rr[s]] + val) : val;
      }
    }
    grid_bar(cnt, (unsigned)(SINK_BLOCKS * (p + 1)));
  }

  // phase 10 (even) wrote buf0; loss by block 0
  if (blockIdx.x == 0) {
    const int t = threadIdx.x;
    double s = 0.0;
    for (int i = t; i < 512; i += 256) {
      s += (exp(-buf0[1024 + i] / RHO_C) - exp(-buf0[i] / RHO_C)) +
           (exp(-buf0[1536 + i] / RHO_C) - exp(-buf0[512 + i] / RHO_C));
    }
#pragma unroll
    for (int off = 32; off > 0; off >>= 1) s += __shfl_xor(s, off);
    __shared__ double wsum[4];
    if ((t & 63) == 0) wsum[t >> 6] = s;
    __syncthreads();
    if (t == 0) {
      const double tot = wsum[0] + wsum[1] + wsum[2] + wsum[3];
      out[0] = (float)((RHO_C + 1e-4 * 0.5) * tot * (1.0 / 512.0));
      for (int i = 1; i < out_size; ++i) out[i] = 0.f;
    }
  }
}

extern "C" void kernel_launch(void* const* d_in, const int* in_sizes, int n_in,
                              void* d_out, int out_size, void* d_ws, size_t ws_size,
                              hipStream_t stream) {
  const float* nd = (const float*)d_in[1];
  const float* gt = (const float*)d_in[2];
  float* out = (float*)d_out;
  char* ws = (char*)d_ws;

  const size_t GM = (size_t)NPTS * NPTS;     // 1M elems
  const size_t P16 = (size_t)NPTS * HW * 2;  // 32 MB per half
  int nsplit = 14;                            // 36*14 = 504 blocks <= 512: no tail
  while (nsplit > 1 &&
         2 * P16 + (size_t)nsplit * NTILES * 16384 * 4 + GM * 4 + 65536 > ws_size)
    nsplit >>= 1;

  _Float16* hi_t = (_Float16*)ws;
  _Float16* lo_t = (_Float16*)(ws + P16);
  float* part = (float*)(ws + 2 * P16);
  const size_t partsz = (size_t)nsplit * NTILES * 16384 * 4;
  float* G = (float*)(ws + 2 * P16 + partsz);
  float* diag = (float*)(ws + 2 * P16 + partsz + GM * 4);
  double* pots = (double*)(ws + 2 * P16 + partsz + GM * 4 + 8192);
  unsigned* cnt = (unsigned*)(ws + 2 * P16 + partsz + GM * 4 + 8192 + 40960);

  hipMemsetAsync(cnt, 0, 64, stream);
  convert_split_k<<<1024, 256, 0, stream>>>(nd, gt, hi_t, lo_t);
  gemm_mfma_k<<<dim3(NTILES, nsplit), 256, 0, stream>>>(hi_t, lo_t, part);
  reduce_tiles_k<<<576, 256, 0, stream>>>(part, G, diag, nsplit);
  sinkhorn_fused_k<<<SINK_BLOCKS, 256, 0, stream>>>(G, diag, pots, cnt, out, out_size);
}

// Round 6
// 192.004 us; speedup vs baseline: 1.8367x; 1.8367x over previous
//
#include <hip/hip_runtime.h>
#include <math.h>

#define HW 16384
#define NPTS 1024
#define LOG_N 6.2383246250395075
#define RHO_C 0.09
#define SCALE_F 16384.0f
#define INV_SCALE2 3.725290298461914e-09  // 2^-28, exact
#define NTILES 36                          // 8x8 upper triangle

typedef _Float16 f16x8 __attribute__((ext_vector_type(8)));
typedef float f32x4 __attribute__((ext_vector_type(4)));

typedef __attribute__((address_space(1))) const void gvoid_t;
typedef __attribute__((address_space(3))) void svoid_t;

__device__ __forceinline__ void tri_map(int tt, int& ti, int& tj) {
  int a = 0, r = tt;
  while (r >= 8 - a) { r -= 8 - a; ++a; }
  ti = a; tj = a + r;
}

// ---------------------------------------------------------------------------
// Convert fp32 P=[nd;gt] (1024 x 16384) into scaled fp16 hi/lo split, stored
// K-tiled: hi_t[k64][row][64], 8-elem groups pre-swizzled by g ^ (row&7) so
// the GEMM's linear global_load_lds yields a conflict-free LDS image.
// ---------------------------------------------------------------------------
__global__ __launch_bounds__(256)
void convert_split_k(const float* __restrict__ nd, const float* __restrict__ gt,
                     _Float16* __restrict__ hi_t, _Float16* __restrict__ lo_t) {
  const int tid = blockIdx.x * 256 + threadIdx.x;  // 0 .. 262143
  const int r = tid & 1023;
  const int k64 = tid >> 10;
  const float* __restrict__ src =
      (r < 512 ? nd + (size_t)r * HW : gt + (size_t)(r - 512) * HW) + k64 * 64;
  const size_t obase = ((size_t)k64 * 1024 + r) * 64;
  const int sw = r & 7;
#pragma unroll
  for (int g = 0; g < 8; ++g) {
    const float4 v0 = *(const float4*)(src + g * 8);
    const float4 v1 = *(const float4*)(src + g * 8 + 4);
    const float x[8] = {v0.x, v0.y, v0.z, v0.w, v1.x, v1.y, v1.z, v1.w};
    f16x8 h, l;
#pragma unroll
    for (int j = 0; j < 8; ++j) {
      const float xs = x[j] * SCALE_F;
      const _Float16 hh = (_Float16)xs;
      h[j] = hh;
      l[j] = (_Float16)(xs - (float)hh);
    }
    *(f16x8*)(hi_t + obase + (size_t)(g ^ sw) * 8) = h;
    *(f16x8*)(lo_t + obase + (size_t)(g ^ sw) * 8) = l;
  }
}

// ---------------------------------------------------------------------------
// Upper-triangle tiles only (G symmetric). 128x128 tile, BK=64, 4 waves,
// 3-pass f16 split MFMA. Split-K: gridDim.y chunks, UNEVEN (q or q+1 k64
// tiles each); 36 x 14 = 504 blocks <= 512 so all blocks co-resident.
// ---------------------------------------------------------------------------
__global__ __launch_bounds__(256)
void gemm_mfma_k(const _Float16* __restrict__ hi_t, const _Float16* __restrict__ lo_t,
                 float* __restrict__ part) {
  __shared__ __align__(16) _Float16 Ahi[128 * 64];
  __shared__ __align__(16) _Float16 Alo[128 * 64];
  __shared__ __align__(16) _Float16 Bhi[128 * 64];
  __shared__ __align__(16) _Float16 Blo[128 * 64];

  const int tt = blockIdx.x, c = blockIdx.y;
  int ti, tj;
  tri_map(tt, ti, tj);
  const int ns = gridDim.y;
  const int q = 256 / ns, rm = 256 - q * ns;
  const int kt0 = c * q + min(c, rm);
  const int nkt = q + (c < rm ? 1 : 0);
  const int t = threadIdx.x;
  const int lane = t & 63, w = t >> 6;
  const int wr = w >> 1, wc = w & 1;

  f32x4 acc[4][4];
#pragma unroll
  for (int m = 0; m < 4; ++m)
#pragma unroll
    for (int n = 0; n < 4; ++n) acc[m][n] = (f32x4){0.f, 0.f, 0.f, 0.f};

  const int rlow = lane & 15, g0 = lane >> 4;

  for (int ks = 0; ks < nkt; ++ks) {
    const size_t ktbase = (size_t)(kt0 + ks) * (1024 * 64);
    const _Float16* __restrict__ sAh = hi_t + ktbase + (size_t)ti * 128 * 64;
    const _Float16* __restrict__ sAl = lo_t + ktbase + (size_t)ti * 128 * 64;
    const _Float16* __restrict__ sBh = hi_t + ktbase + (size_t)tj * 128 * 64;
    const _Float16* __restrict__ sBl = lo_t + ktbase + (size_t)tj * 128 * 64;
#pragma unroll
    for (int p = 0; p < 4; ++p) {
      const int off = (w * 4 + p) * 1024 + lane * 16;  // bytes
      __builtin_amdgcn_global_load_lds((gvoid_t*)((const char*)sAh + off),
                                       (svoid_t*)((char*)Ahi + (w * 4 + p) * 1024), 16, 0, 0);
      __builtin_amdgcn_global_load_lds((gvoid_t*)((const char*)sAl + off),
                                       (svoid_t*)((char*)Alo + (w * 4 + p) * 1024), 16, 0, 0);
      __builtin_amdgcn_global_load_lds((gvoid_t*)((const char*)sBh + off),
                                       (svoid_t*)((char*)Bhi + (w * 4 + p) * 1024), 16, 0, 0);
      __builtin_amdgcn_global_load_lds((gvoid_t*)((const char*)sBl + off),
                                       (svoid_t*)((char*)Blo + (w * 4 + p) * 1024), 16, 0, 0);
    }
    __syncthreads();

#pragma unroll
    for (int kk = 0; kk < 2; ++kk) {
      const int g = kk * 4 + g0;
      f16x8 fah[4], fal[4], fbh[4], fbl[4];
#pragma unroll
      for (int m = 0; m < 4; ++m) {
        const int ra = wr * 64 + m * 16 + rlow;
        const int pa = (g ^ (ra & 7)) * 8;
        fah[m] = *(const f16x8*)(Ahi + ra * 64 + pa);
        fal[m] = *(const f16x8*)(Alo + ra * 64 + pa);
        const int rb = wc * 64 + m * 16 + rlow;
        const int pb = (g ^ (rb & 7)) * 8;
        fbh[m] = *(const f16x8*)(Bhi + rb * 64 + pb);
        fbl[m] = *(const f16x8*)(Blo + rb * 64 + pb);
      }
#pragma unroll
      for (int m = 0; m < 4; ++m)
#pragma unroll
        for (int n = 0; n < 4; ++n) {
          acc[m][n] = __builtin_amdgcn_mfma_f32_16x16x32_f16(fah[m], fbh[n], acc[m][n], 0, 0, 0);
          acc[m][n] = __builtin_amdgcn_mfma_f32_16x16x32_f16(fal[m], fbh[n], acc[m][n], 0, 0, 0);
          acc[m][n] = __builtin_amdgcn_mfma_f32_16x16x32_f16(fah[m], fbl[n], acc[m][n], 0, 0, 0);
        }
    }
    __syncthreads();
  }

  // C/D layout: col = lane&15, row = (lane>>4)*4 + q (m89-verified)
  float* __restrict__ dst = part + ((size_t)c * NTILES + tt) * 16384;
  const int c_locb = wc * 64 + rlow;
  const int r_locb = wr * 64 + g0 * 4;
#pragma unroll
  for (int m = 0; m < 4; ++m)
#pragma unroll
    for (int p = 0; p < 4; ++p) {
      const int rl = r_locb + m * 16 + p;
#pragma unroll
      for (int n = 0; n < 4; ++n)
        dst[rl * 128 + c_locb + n * 16] = acc[m][n][p];
    }
}

// ---------------------------------------------------------------------------
// Sum split-K partials (fp64), unscale, write G tile + mirrored tile (LDS
// transpose), extract diagonal. Grid: 36 tiles x 16 slabs of 8 rows = 576.
// ---------------------------------------------------------------------------
__global__ __launch_bounds__(256)
void reduce_tiles_k(const float* __restrict__ part, float* __restrict__ G,
                    float* __restrict__ diag, int nsplit) {
  __shared__ float sl[8][129];
  const int blk = blockIdx.x;  // 0..575
  const int tt = blk >> 4, s = blk & 15;
  int ti, tj;
  tri_map(tt, ti, tj);
  const int t = threadIdx.x;
  const int base_in = tt * 16384 + s * 1024;

  float vals[4];
#pragma unroll
  for (int j = 0; j < 4; ++j) {
    const int idx = j * 256 + t;  // 0..1023 within slab
    double a = 0.0;
    for (int c = 0; c < nsplit; ++c)
      a += (double)part[(size_t)c * (NTILES * 16384) + base_in + idx];
    vals[j] = (float)(a * INV_SCALE2);
  }
#pragma unroll
  for (int j = 0; j < 4; ++j) {
    const int idx = j * 256 + t;
    const int r = idx >> 7, cl = idx & 127;
    const int R = ti * 128 + s * 8 + r, C = tj * 128 + cl;
    G[(size_t)R * NPTS + C] = vals[j];
    if (R == C) diag[R] = vals[j];
    sl[r][cl] = vals[j];
  }
  if (ti == tj) return;
  __syncthreads();
#pragma unroll
  for (int j = 0; j < 4; ++j) {
    const int idx = j * 256 + t;
    const int r = idx & 7, cl = idx >> 3;
    G[(size_t)(tj * 128 + cl) * NPTS + ti * 128 + s * 8 + r] = sl[r][cl];
  }
}

// ---------------------------------------------------------------------------
// One symmetric Sinkhorn phase: 512 blocks x 4 waves; 1 wave = 1 row-task.
// pot layout: [0]=f_ba, [1]=g_ab, [2]=f_aa, [3]=g_bb (512 doubles each).
// ---------------------------------------------------------------------------
__global__ __launch_bounds__(256)
void sinkhorn_phase_k(const float* __restrict__ G, const float* __restrict__ diag,
                      const double* __restrict__ src, double* __restrict__ dst,
                      double eps, double inv_eps, double damp, int use_pot,
                      int do_avg) {
  const int w = threadIdx.x >> 6, lane = threadIdx.x & 63;
  const int id = blockIdx.x * 4 + w;  // 0..2047
  const int which = id >> 9, r = id & 511;
  int row_pt, col_base, pot_idx;
  if (which == 0)      { row_pt = r;       col_base = 512; pot_idx = 1; }
  else if (which == 1) { row_pt = 512 + r; col_base = 0;   pot_idx = 0; }
  else if (which == 2) { row_pt = r;       col_base = 0;   pot_idx = 2; }
  else                 { row_pt = 512 + r; col_base = 512; pot_idx = 3; }

  const double dr = (double)diag[row_pt];
  const double* __restrict__ pot = src + pot_idx * 512;
  const float* __restrict__ Grow = G + (size_t)row_pt * NPTS + col_base;
  const float* __restrict__ dcol = diag + col_base;

  double arg[8];
  double m = -1.0e300;
#pragma unroll
  for (int u = 0; u < 8; ++u) {
    const int j = lane + u * 64;
    const double C = 0.5 * (dr + (double)dcol[j]) - (double)Grow[j];
    const double p = use_pot ? pot[j] : 0.0;
    const double a = (p - C) * inv_eps - LOG_N;
    arg[u] = a;
    m = fmax(m, a);
  }
#pragma unroll
  for (int off = 32; off > 0; off >>= 1) m = fmax(m, __shfl_xor(m, off));
  double s = 0.0;
#pragma unroll
  for (int u = 0; u < 8; ++u) s += exp(arg[u] - m);
#pragma unroll
  for (int off = 32; off > 0; off >>= 1) s += __shfl_xor(s, off);
  if (lane == 0) {
    const double lse = m + log(s);
    const double val = -eps * lse * damp;
    dst[which * 512 + r] = do_avg ? 0.5 * (src[which * 512 + r] + val) : val;
  }
}

// ---------------------------------------------------------------------------
// Debiased unbalanced Sinkhorn loss.
// ---------------------------------------------------------------------------
__global__ __launch_bounds__(256)
void loss_k(const double* __restrict__ pot, float* __restrict__ out, int out_size,
            double w) {
  const int t = threadIdx.x;
  double s = 0.0;
  for (int i = t; i < 512; i += 256) {
    s += (exp(-pot[1024 + i] / RHO_C) - exp(-pot[i] / RHO_C)) +
         (exp(-pot[1536 + i] / RHO_C) - exp(-pot[512 + i] / RHO_C));
  }
#pragma unroll
  for (int off = 32; off > 0; off >>= 1) s += __shfl_xor(s, off);
  __shared__ double wsum[4];
  if ((t & 63) == 0) wsum[t >> 6] = s;
  __syncthreads();
  if (t == 0) {
    out[0] = (float)(w * (wsum[0] + wsum[1] + wsum[2] + wsum[3]) * (1.0 / 512.0));
    for (int i = 1; i < out_size; ++i) out[i] = 0.f;
  }
}

extern "C" void kernel_launch(void* const* d_in, const int* in_sizes, int n_in,
                              void* d_out, int out_size, void* d_ws, size_t ws_size,
                              hipStream_t stream) {
  const float* nd = (const float*)d_in[1];
  const float* gt = (const float*)d_in[2];
  float* out = (float*)d_out;
  char* ws = (char*)d_ws;

  const size_t GM = (size_t)NPTS * NPTS;     // 1M elems
  const size_t P16 = (size_t)NPTS * HW * 2;  // 32 MB per half
  int nsplit = 14;                            // 36*14 = 504 blocks <= 512: no tail
  while (nsplit > 1 &&
         2 * P16 + (size_t)nsplit * NTILES * 16384 * 4 + GM * 4 + 65536 > ws_size)
    nsplit >>= 1;

  _Float16* hi_t = (_Float16*)ws;
  _Float16* lo_t = (_Float16*)(ws + P16);
  float* part = (float*)(ws + 2 * P16);
  const size_t partsz = (size_t)nsplit * NTILES * 16384 * 4;
  float* G = (float*)(ws + 2 * P16 + partsz);
  float* diag = (float*)(ws + 2 * P16 + partsz + GM * 4);
  double* pots = (double*)(ws + 2 * P16 + partsz + GM * 4 + 8192);

  convert_split_k<<<1024, 256, 0, stream>>>(nd, gt, hi_t, lo_t);
  gemm_mfma_k<<<dim3(NTILES, nsplit), 256, 0, stream>>>(hi_t, lo_t, part);
  reduce_tiles_k<<<576, 256, 0, stream>>>(part, G, diag, nsplit);

  const double eps_list[9] = {1.0, 1.0, 0.25, 0.0625, 0.015625,
                              0.00390625, 0.0009765625, 0.000244140625, 1e-4};
  double* p0 = pots;
  double* p1 = pots + 2048;
  {  // init at eps0 = 1.0, no inner potentials, no averaging
    const double eps = 1.0, d = 1.0 / (1.0 + eps / RHO_C);
    sinkhorn_phase_k<<<512, 256, 0, stream>>>(G, diag, p1, p0, eps, 1.0 / eps, d, 0, 0);
  }
  double* src = p0;
  double* dst = p1;
  for (int k = 0; k < 9; ++k) {  // symmetric averaged updates
    const double eps = eps_list[k], d = 1.0 / (1.0 + eps / RHO_C);
    sinkhorn_phase_k<<<512, 256, 0, stream>>>(G, diag, src, dst, eps, 1.0 / eps, d, 1, 1);
    double* tmp = src; src = dst; dst = tmp;
  }
  {  // final extrapolation at blur^2, no averaging
    const double eps = 1e-4, d = 1.0 / (1.0 + eps / RHO_C);
    sinkhorn_phase_k<<<512, 256, 0, stream>>>(G, diag, src, dst, eps, 1.0 / eps, d, 1, 0);
    double* tmp = src; src = dst; dst = tmp;
  }
  loss_k<<<1, 256, 0, stream>>>(src, out, out_size, RHO_C + 1e-4 * 0.5);
}

// Round 7
// 189.644 us; speedup vs baseline: 1.8595x; 1.0124x over previous
//
#include <hip/hip_runtime.h>
#include <math.h>

#define HW 16384
#define NPTS 1024
#define LOG_N 6.2383246250395075
#define RHO_C 0.09
#define SCALE_F 16384.0f
#define INV_SCALE2 3.725290298461914e-09  // 2^-28, exact
#define NTILES 36                          // 8x8 upper triangle

typedef _Float16 f16x8 __attribute__((ext_vector_type(8)));
typedef float f32x4 __attribute__((ext_vector_type(4)));

__device__ __forceinline__ void tri_map(int tt, int& ti, int& tj) {
  int a = 0, r = tt;
  while (r >= 8 - a) { r -= 8 - a; ++a; }
  ti = a; tj = a + r;
}

// ---------------------------------------------------------------------------
// Convert fp32 P=[nd;gt] (1024 x 16384) into scaled fp16 hi/lo split, stored
// fragment-native: hi2[k64][kk(2)][row(1024)][32], so a GEMM wave's MFMA
// fragment load (16 rows x 64B) is one contiguous 1KB region -> perfectly
// coalesced global_load_dwordx4 direct to registers (no LDS at all).
// x_s = x*2^14 = hi + lo (exact residual; undone by 2^-28 in fp64 reduce).
// ---------------------------------------------------------------------------
__global__ __launch_bounds__(256)
void convert_split_k(const float* __restrict__ nd, const float* __restrict__ gt,
                     _Float16* __restrict__ hi2, _Float16* __restrict__ lo2) {
  const int tid = blockIdx.x * 256 + threadIdx.x;  // 0 .. 262143
  const int r = tid & 1023;
  const int k64 = tid >> 10;
  const float* __restrict__ src =
      (r < 512 ? nd + (size_t)r * HW : gt + (size_t)(r - 512) * HW) + k64 * 64;
  const size_t ob = ((size_t)k64 * 2048 + r) * 32;  // kk=0 slab; kk=1 at +1024*32
#pragma unroll
  for (int g = 0; g < 8; ++g) {
    const float4 v0 = *(const float4*)(src + g * 8);
    const float4 v1 = *(const float4*)(src + g * 8 + 4);
    const float x[8] = {v0.x, v0.y, v0.z, v0.w, v1.x, v1.y, v1.z, v1.w};
    f16x8 h, l;
#pragma unroll
    for (int j = 0; j < 8; ++j) {
      const float xs = x[j] * SCALE_F;
      const _Float16 hh = (_Float16)xs;
      h[j] = hh;
      l[j] = (_Float16)(xs - (float)hh);
    }
    const size_t o = ob + (size_t)(g >> 2) * (1024 * 32) + (g & 3) * 8;
    *(f16x8*)(hi2 + o) = h;
    *(f16x8*)(lo2 + o) = l;
  }
}

// ---------------------------------------------------------------------------
// Upper-triangle tiles only (G symmetric). 128x128 tile, 4 waves (2x2),
// 3-pass f16 split MFMA (hh + lh + hl). NO LDS: fragments loaded straight
// from global (fragment-native layout) into registers; no __syncthreads,
// so the compiler pipelines buffer loads against MFMA via vmcnt freely.
// Split-K uneven so 36 x 14 = 504 blocks <= 512: all co-resident.
// ---------------------------------------------------------------------------
__global__ __launch_bounds__(256, 2)
void gemm_mfma_k(const _Float16* __restrict__ hi2, const _Float16* __restrict__ lo2,
                 float* __restrict__ part) {
  const int tt = blockIdx.x, c = blockIdx.y;
  int ti, tj;
  tri_map(tt, ti, tj);
  const int ns = gridDim.y;
  const int q = 256 / ns, rm = 256 - q * ns;
  const int kt0 = c * q + min(c, rm);
  const int nkt = q + (c < rm ? 1 : 0);
  const int t = threadIdx.x;
  const int lane = t & 63, w = t >> 6;
  const int wr = w >> 1, wc = w & 1;
  const int rlow = lane & 15, g0 = lane >> 4;

  f32x4 acc[4][4];
#pragma unroll
  for (int m = 0; m < 4; ++m)
#pragma unroll
    for (int n = 0; n < 4; ++n) acc[m][n] = (f32x4){0.f, 0.f, 0.f, 0.f};

  const size_t laneoff = (size_t)rlow * 32 + (size_t)g0 * 8;
  const size_t abase = (size_t)(ti * 128 + wr * 64) * 32 + laneoff;
  const size_t bbase = (size_t)(tj * 128 + wc * 64) * 32 + laneoff;

  for (int ks = 0; ks < nkt; ++ks) {
#pragma unroll
    for (int kk = 0; kk < 2; ++kk) {
      const size_t slab = ((size_t)(kt0 + ks) * 2 + kk) * (size_t)(1024 * 32);
      f16x8 fah[4], fal[4], fbh[4], fbl[4];
#pragma unroll
      for (int m = 0; m < 4; ++m) {
        fah[m] = *(const f16x8*)(hi2 + slab + abase + (size_t)m * 512);
        fal[m] = *(const f16x8*)(lo2 + slab + abase + (size_t)m * 512);
        fbh[m] = *(const f16x8*)(hi2 + slab + bbase + (size_t)m * 512);
        fbl[m] = *(const f16x8*)(lo2 + slab + bbase + (size_t)m * 512);
      }
#pragma unroll
      for (int m = 0; m < 4; ++m)
#pragma unroll
        for (int n = 0; n < 4; ++n) {
          acc[m][n] = __builtin_amdgcn_mfma_f32_16x16x32_f16(fah[m], fbh[n], acc[m][n], 0, 0, 0);
          acc[m][n] = __builtin_amdgcn_mfma_f32_16x16x32_f16(fal[m], fbh[n], acc[m][n], 0, 0, 0);
          acc[m][n] = __builtin_amdgcn_mfma_f32_16x16x32_f16(fah[m], fbl[n], acc[m][n], 0, 0, 0);
        }
    }
  }

  // C/D layout: col = lane&15, row = (lane>>4)*4 + q (m89-verified)
  float* __restrict__ dst = part + ((size_t)c * NTILES + tt) * 16384;
  const int c_locb = wc * 64 + rlow;
  const int r_locb = wr * 64 + g0 * 4;
#pragma unroll
  for (int m = 0; m < 4; ++m)
#pragma unroll
    for (int p = 0; p < 4; ++p) {
      const int rl = r_locb + m * 16 + p;
#pragma unroll
      for (int n = 0; n < 4; ++n)
        dst[rl * 128 + c_locb + n * 16] = acc[m][n][p];
    }
}

// ---------------------------------------------------------------------------
// Sum split-K partials (fp64), unscale, write G tile + mirrored tile (LDS
// transpose), extract diagonal. Grid: 36 tiles x 16 slabs of 8 rows = 576.
// ---------------------------------------------------------------------------
__global__ __launch_bounds__(256)
void reduce_tiles_k(const float* __restrict__ part, float* __restrict__ G,
                    float* __restrict__ diag, int nsplit) {
  __shared__ float sl[8][129];
  const int blk = blockIdx.x;  // 0..575
  const int tt = blk >> 4, s = blk & 15;
  int ti, tj;
  tri_map(tt, ti, tj);
  const int t = threadIdx.x;
  const int base_in = tt * 16384 + s * 1024;

  float vals[4];
#pragma unroll
  for (int j = 0; j < 4; ++j) {
    const int idx = j * 256 + t;  // 0..1023 within slab
    double a = 0.0;
    for (int c = 0; c < nsplit; ++c)
      a += (double)part[(size_t)c * (NTILES * 16384) + base_in + idx];
    vals[j] = (float)(a * INV_SCALE2);
  }
#pragma unroll
  for (int j = 0; j < 4; ++j) {
    const int idx = j * 256 + t;
    const int r = idx >> 7, cl = idx & 127;
    const int R = ti * 128 + s * 8 + r, C = tj * 128 + cl;
    G[(size_t)R * NPTS + C] = vals[j];
    if (R == C) diag[R] = vals[j];
    sl[r][cl] = vals[j];
  }
  if (ti == tj) return;
  __syncthreads();
#pragma unroll
  for (int j = 0; j < 4; ++j) {
    const int idx = j * 256 + t;
    const int r = idx & 7, cl = idx >> 3;
    G[(size_t)(tj * 128 + cl) * NPTS + ti * 128 + s * 8 + r] = sl[r][cl];
  }
}

// ---------------------------------------------------------------------------
// One symmetric Sinkhorn phase: 512 blocks x 4 waves; 1 wave = 1 row-task.
// pot layout: [0]=f_ba, [1]=g_ab, [2]=f_aa, [3]=g_bb (512 doubles each).
// ---------------------------------------------------------------------------
__global__ __launch_bounds__(256)
void sinkhorn_phase_k(const float* __restrict__ G, const float* __restrict__ diag,
                      const double* __restrict__ src, double* __restrict__ dst,
                      double eps, double inv_eps, double damp, int use_pot,
                      int do_avg) {
  const int w = threadIdx.x >> 6, lane = threadIdx.x & 63;
  const int id = blockIdx.x * 4 + w;  // 0..2047
  const int which = id >> 9, r = id & 511;
  int row_pt, col_base, pot_idx;
  if (which == 0)      { row_pt = r;       col_base = 512; pot_idx = 1; }
  else if (which == 1) { row_pt = 512 + r; col_base = 0;   pot_idx = 0; }
  else if (which == 2) { row_pt = r;       col_base = 0;   pot_idx = 2; }
  else                 { row_pt = 512 + r; col_base = 512; pot_idx = 3; }

  const double dr = (double)diag[row_pt];
  const double* __restrict__ pot = src + pot_idx * 512;
  const float* __restrict__ Grow = G + (size_t)row_pt * NPTS + col_base;
  const float* __restrict__ dcol = diag + col_base;

  double arg[8];
  double m = -1.0e300;
#pragma unroll
  for (int u = 0; u < 8; ++u) {
    const int j = lane + u * 64;
    const double C = 0.5 * (dr + (double)dcol[j]) - (double)Grow[j];
    const double p = use_pot ? pot[j] : 0.0;
    const double a = (p - C) * inv_eps - LOG_N;
    arg[u] = a;
    m = fmax(m, a);
  }
#pragma unroll
  for (int off = 32; off > 0; off >>= 1) m = fmax(m, __shfl_xor(m, off));
  double s = 0.0;
#pragma unroll
  for (int u = 0; u < 8; ++u) s += exp(arg[u] - m);
#pragma unroll
  for (int off = 32; off > 0; off >>= 1) s += __shfl_xor(s, off);
  if (lane == 0) {
    const double lse = m + log(s);
    const double val = -eps * lse * damp;
    dst[which * 512 + r] = do_avg ? 0.5 * (src[which * 512 + r] + val) : val;
  }
}

// ---------------------------------------------------------------------------
// Debiased unbalanced Sinkhorn loss.
// ---------------------------------------------------------------------------
__global__ __launch_bounds__(256)
void loss_k(const double* __restrict__ pot, float* __restrict__ out, int out_size,
            double w) {
  const int t = threadIdx.x;
  double s = 0.0;
  for (int i = t; i < 512; i += 256) {
    s += (exp(-pot[1024 + i] / RHO_C) - exp(-pot[i] / RHO_C)) +
         (exp(-pot[1536 + i] / RHO_C) - exp(-pot[512 + i] / RHO_C));
  }
#pragma unroll
  for (int off = 32; off > 0; off >>= 1) s += __shfl_xor(s, off);
  __shared__ double wsum[4];
  if ((t & 63) == 0) wsum[t >> 6] = s;
  __syncthreads();
  if (t == 0) {
    out[0] = (float)(w * (wsum[0] + wsum[1] + wsum[2] + wsum[3]) * (1.0 / 512.0));
    for (int i = 1; i < out_size; ++i) out[i] = 0.f;
  }
}

extern "C" void kernel_launch(void* const* d_in, const int* in_sizes, int n_in,
                              void* d_out, int out_size, void* d_ws, size_t ws_size,
                              hipStream_t stream) {
  const float* nd = (const float*)d_in[1];
  const float* gt = (const float*)d_in[2];
  float* out = (float*)d_out;
  char* ws = (char*)d_ws;

  const size_t GM = (size_t)NPTS * NPTS;     // 1M elems
  const size_t P16 = (size_t)NPTS * HW * 2;  // 32 MB per half
  int nsplit = 14;                            // 36*14 = 504 blocks <= 512: no tail
  while (nsplit > 1 &&
         2 * P16 + (size_t)nsplit * NTILES * 16384 * 4 + GM * 4 + 65536 > ws_size)
    nsplit >>= 1;

  _Float16* hi2 = (_Float16*)ws;
  _Float16* lo2 = (_Float16*)(ws + P16);
  float* part = (float*)(ws + 2 * P16);
  const size_t partsz = (size_t)nsplit * NTILES * 16384 * 4;
  float* G = (float*)(ws + 2 * P16 + partsz);
  float* diag = (float*)(ws + 2 * P16 + partsz + GM * 4);
  double* pots = (double*)(ws + 2 * P16 + partsz + GM * 4 + 8192);

  convert_split_k<<<1024, 256, 0, stream>>>(nd, gt, hi2, lo2);
  gemm_mfma_k<<<dim3(NTILES, nsplit), 256, 0, stream>>>(hi2, lo2, part);
  reduce_tiles_k<<<576, 256, 0, stream>>>(part, G, diag, nsplit);

  const double eps_list[9] = {1.0, 1.0, 0.25, 0.0625, 0.015625,
                              0.00390625, 0.0009765625, 0.000244140625, 1e-4};
  double* p0 = pots;
  double* p1 = pots + 2048;
  {  // init at eps0 = 1.0, no inner potentials, no averaging
    const double eps = 1.0, d = 1.0 / (1.0 + eps / RHO_C);
    sinkhorn_phase_k<<<512, 256, 0, stream>>>(G, diag, p1, p0, eps, 1.0 / eps, d, 0, 0);
  }
  double* src = p0;
  double* dst = p1;
  for (int k = 0; k < 9; ++k) {  // symmetric averaged updates
    const double eps = eps_list[k], d = 1.0 / (1.0 + eps / RHO_C);
    sinkhorn_phase_k<<<512, 256, 0, stream>>>(G, diag, src, dst, eps, 1.0 / eps, d, 1, 1);
    double* tmp = src; src = dst; dst = tmp;
  }
  {  // final extrapolation at blur^2, no averaging
    const double eps = 1e-4, d = 1.0 / (1.0 + eps / RHO_C);
    sinkhorn_phase_k<<<512, 256, 0, stream>>>(G, diag, src, dst, eps, 1.0 / eps, d, 1, 0);
    double* tmp = src; src = dst; dst = tmp;
  }
  loss_k<<<1, 256, 0, stream>>>(src, out, out_size, RHO_C + 1e-4 * 0.5);
}